// Round 11
// baseline (389.301 us; speedup 1.0000x reference)
//
#include <hip/hip_runtime.h>
#include <hip/hip_bf16.h>

#define N 8192
#define D 768
#define TEMP_INV 20.0f

typedef __attribute__((ext_vector_type(4))) float f32x4;
typedef __attribute__((ext_vector_type(4))) int i32x4;
typedef __attribute__((ext_vector_type(8))) int i32x8;

#define SCALE1 0x7F7F7F7F  // e8m0 = 127 in all 4 bytes -> scale 1.0

// Workspace layout (floats):
//   [0,   N)     rowsum   (zeroed by norm_kernel)
//   [N,  2N)     pos      (fully written by sim_kernel diag tiles)
//   [2N, 2N+16)  pad
//   [2N+16, ...) xn fp8-e4m3, PRE-SHUFFLED fragment-major layout:
//     16-row panel p, kc: fragment block of 2048 B at p*12288 + kc*2048;
//     within: lo 1024 B = lane*16 (lane = q*16 + cl), hi 1024 B likewise.
//     -> one MFMA fragment = two contiguous, lane-ordered 1024 B blocks.

// ---------------------------------------------------------------------------
// Kernel 1: row L2-normalize fp32 -> fp8 e4m3 in pre-shuffled layout (R8).
__global__ __launch_bounds__(256) void norm_kernel(
    const float* __restrict__ x, unsigned char* __restrict__ xn,
    float* __restrict__ rowsum) {
  int t = threadIdx.x, w = t >> 6, lane = t & 63;
  int p = blockIdx.x;  // panel
  __shared__ unsigned int lds[3072];  // 12 KB panel staging
#pragma unroll
  for (int it = 0; it < 4; ++it) {
    int r = w * 4 + it;
    const float4* xr = (const float4*)(x + (size_t)(p * 16 + r) * D);
    float4 v[3];
    v[0] = xr[lane];
    v[1] = xr[lane + 64];
    v[2] = xr[lane + 128];
    float ss = 0.0f;
#pragma unroll
    for (int i = 0; i < 3; ++i)
      ss += v[i].x * v[i].x + v[i].y * v[i].y + v[i].z * v[i].z + v[i].w * v[i].w;
#pragma unroll
    for (int m = 32; m; m >>= 1) ss += __shfl_xor(ss, m);
    float inv = 1.0f / fmaxf(sqrtf(ss), 1e-8f);
#pragma unroll
    for (int i = 0; i < 3; ++i) {
      int pk = __builtin_amdgcn_cvt_pk_fp8_f32(v[i].x * inv, v[i].y * inv, 0, false);
      pk = __builtin_amdgcn_cvt_pk_fp8_f32(v[i].z * inv, v[i].w * inv, pk, true);
      int d = lane + 64 * i;  // dword index within row (0..191)
      int kc = d >> 5, dd = d & 31;
      int qq = dd >> 3, h = (dd >> 2) & 1, o4 = d & 3;
      lds[kc * 512 + h * 256 + (qq * 16 + r) * 4 + o4] = (unsigned int)pk;
    }
  }
  __syncthreads();
  const uint4* ls = (const uint4*)lds;
  uint4* dst = (uint4*)(xn + (size_t)p * 12288);
#pragma unroll
  for (int j = 0; j < 3; ++j) dst[t + 256 * j] = ls[t + 256 * j];
  if (t < 16) rowsum[p * 16 + t] = 0.0f;
}

// ---------------------------------------------------------------------------
// Kernel 2: S = Xn*Xn^T upper triangle via MX-scaled fp8 MFMA (K=128,
// scales=1.0). Two unit types, uniform 512 threads / 8 waves:
//   blocks [0,96):   small = single 128x128 tile from diagonal supertiles
//                    (3 per diag supertile; handles diag mask + pos)
//   blocks [96,592): big   = off-diagonal 2x2-tile supertile (256x256):
//                    stages 4 panel-pairs ONCE for 4 tiles of MFMA ->
//                    halves glds-staged bytes/elem (the measured 6.5 TB/s
//                    staging wall from rounds 2-6).
// Pre-shuffled layout => glds lands fragment-ordered in LDS; fragment reads
// are linear lane*16 b128s (baseline pattern, no bank conflicts).
__global__ __launch_bounds__(512, 2) void sim_kernel(
    const unsigned char* __restrict__ xn, float* __restrict__ rowsum,
    float* __restrict__ pos) {
  __shared__ __align__(16) unsigned char lds[65536];

  int b = blockIdx.x;
  int t = threadIdx.x;
  int w = t >> 6, lane = t & 63;
  int q = lane >> 4, cl = lane & 15;
  int wi = w >> 1, wj = w & 1;
  union Frag { i32x8 v8; struct { i32x4 lo, hi; } pr; };

  if (b < 96) {
    // ---------------- small unit: one 128x128 tile ----------------
    int s = (b & 7) * 12 + (b >> 3);       // XCD-round-robin -> linear id
    int d = s / 3, k = s - 3 * d;          // diag supertile, member 0..2
    int bi = 2 * d + (k == 2);
    int bj = 2 * d + (k >= 1);

    f32x4 acc[2][4] = {};
    const unsigned char* Ag = xn + (size_t)(bi * 8) * 12288;
    const unsigned char* Bg = xn + (size_t)(bj * 8) * 12288;

    for (int kc = 0; kc < 6; ++kc) {
#pragma unroll
      for (int r = 0; r < 4; ++r) {
        int fb = r * 4 + (t >> 7);  // 0..15: A panels 0-7, B panels 8-15
        const unsigned char* src =
            ((fb < 8) ? (Ag + (size_t)fb * 12288)
                      : (Bg + (size_t)(fb - 8) * 12288)) +
            kc * 2048 + (t & 127) * 16;
        __builtin_amdgcn_global_load_lds(
            (const __attribute__((address_space(1))) unsigned int*)src,
            (__attribute__((address_space(3))) unsigned int*)(lds + r * 8192 + t * 16),
            16, 0, 0);
      }
      __syncthreads();
      Frag a[2];
#pragma unroll
      for (int m = 0; m < 2; ++m) {
        const unsigned char* base = lds + (2 * wi + m) * 2048 + lane * 16;
        a[m].pr.lo = *(const i32x4*)base;
        a[m].pr.hi = *(const i32x4*)(base + 1024);
      }
#pragma unroll
      for (int n = 0; n < 4; ++n) {
        const unsigned char* base = lds + (8 + 4 * wj + n) * 2048 + lane * 16;
        Frag bf;
        bf.pr.lo = *(const i32x4*)base;
        bf.pr.hi = *(const i32x4*)(base + 1024);
#pragma unroll
        for (int m = 0; m < 2; ++m)
          acc[m][n] = __builtin_amdgcn_mfma_scale_f32_16x16x128_f8f6f4(
              a[m].v8, bf.v8, acc[m][n], 0, 0, 0, SCALE1, 0, SCALE1);
      }
      __syncthreads();
    }

    int gi0 = bi * 128 + wi * 32;
    int gj0 = bj * 128 + wj * 64;
    float rowp[2][4] = {};
    float colp[4] = {};
    if (bi == bj) {
#pragma unroll
      for (int m = 0; m < 2; ++m)
#pragma unroll
        for (int n = 0; n < 4; ++n)
#pragma unroll
          for (int r = 0; r < 4; ++r) {
            float sv = acc[m][n][r];
            int row = gi0 + m * 16 + q * 4 + r;
            int col = gj0 + n * 16 + cl;
            float e = __expf(TEMP_INV * sv - 20.0f);
            if (col == row) e = 0.0f;
            if (col == (row ^ 1)) pos[row] = TEMP_INV * sv;
            rowp[m][r] += e;
          }
    } else {
#pragma unroll
      for (int m = 0; m < 2; ++m)
#pragma unroll
        for (int n = 0; n < 4; ++n)
#pragma unroll
          for (int r = 0; r < 4; ++r) {
            float e = __expf(TEMP_INV * acc[m][n][r] - 20.0f);
            rowp[m][r] += e;
            colp[n] += e;
          }
    }
#pragma unroll
    for (int m = 0; m < 2; ++m)
#pragma unroll
      for (int r = 0; r < 4; ++r) {
        float v = rowp[m][r];
        v += __shfl_xor(v, 1);
        v += __shfl_xor(v, 2);
        v += __shfl_xor(v, 4);
        v += __shfl_xor(v, 8);
        if (cl == 0) atomicAdd(&rowsum[gi0 + m * 16 + q * 4 + r], v);
      }
    if (bi != bj) {
#pragma unroll
      for (int n = 0; n < 4; ++n) {
        float v = colp[n];
        v += __shfl_xor(v, 16);
        v += __shfl_xor(v, 32);
        if (q == 0) atomicAdd(&rowsum[gj0 + n * 16 + cl], v);
      }
    }
  } else {
    // ---------------- big unit: off-diag 2x2-tile supertile ----------------
    int e = (b & 7) * 62 + ((b - 96) >> 3);  // 0..495 -> lex (SI<SJ)
    int SI = 0, base = 0;
    while (base + (31 - SI) <= e) { base += 31 - SI; ++SI; }
    int SJ = SI + 1 + (e - base);

    f32x4 acc[4][8] = {};
    const unsigned char* Ag = xn + (size_t)(SI * 16) * 12288;
    const unsigned char* Bg = xn + (size_t)(SJ * 16) * 12288;

    for (int kc = 0; kc < 6; ++kc) {
#pragma unroll
      for (int r = 0; r < 8; ++r) {
        int fb = r * 4 + (t >> 7);  // 0..31: A panels 0-15, B panels 16-31
        const unsigned char* src =
            ((fb < 16) ? (Ag + (size_t)fb * 12288)
                       : (Bg + (size_t)(fb - 16) * 12288)) +
            kc * 2048 + (t & 127) * 16;
        __builtin_amdgcn_global_load_lds(
            (const __attribute__((address_space(1))) unsigned int*)src,
            (__attribute__((address_space(3))) unsigned int*)(lds + r * 8192 + t * 16),
            16, 0, 0);
      }
      __syncthreads();
      Frag a[4];
#pragma unroll
      for (int m = 0; m < 4; ++m) {
        const unsigned char* bp = lds + (4 * wi + m) * 2048 + lane * 16;
        a[m].pr.lo = *(const i32x4*)bp;
        a[m].pr.hi = *(const i32x4*)(bp + 1024);
      }
#pragma unroll
      for (int n = 0; n < 8; ++n) {
        const unsigned char* bp = lds + (16 + 8 * wj + n) * 2048 + lane * 16;
        Frag bf;
        bf.pr.lo = *(const i32x4*)bp;
        bf.pr.hi = *(const i32x4*)(bp + 1024);
#pragma unroll
        for (int m = 0; m < 4; ++m)
          acc[m][n] = __builtin_amdgcn_mfma_scale_f32_16x16x128_f8f6f4(
              a[m].v8, bf.v8, acc[m][n], 0, 0, 0, SCALE1, 0, SCALE1);
      }
      __syncthreads();
    }

    int gi0 = SI * 256 + wi * 64;
    int gj0 = SJ * 256 + wj * 128;
    float rowp[4][4] = {};
    float colp[8] = {};
#pragma unroll
    for (int m = 0; m < 4; ++m)
#pragma unroll
      for (int n = 0; n < 8; ++n)
#pragma unroll
        for (int r = 0; r < 4; ++r) {
          float e2 = __expf(TEMP_INV * acc[m][n][r] - 20.0f);
          rowp[m][r] += e2;
          colp[n] += e2;
        }
#pragma unroll
    for (int m = 0; m < 4; ++m)
#pragma unroll
      for (int r = 0; r < 4; ++r) {
        float v = rowp[m][r];
        v += __shfl_xor(v, 1);
        v += __shfl_xor(v, 2);
        v += __shfl_xor(v, 4);
        v += __shfl_xor(v, 8);
        if (cl == 0) atomicAdd(&rowsum[gi0 + m * 16 + q * 4 + r], v);
      }
#pragma unroll
    for (int n = 0; n < 8; ++n) {
      float v = colp[n];
      v += __shfl_xor(v, 16);
      v += __shfl_xor(v, 32);
      if (q == 0) atomicAdd(&rowsum[gj0 + n * 16 + cl], v);
    }
  }
}

// ---------------------------------------------------------------------------
// Kernel 3: loss = mean_i (20 + log(rowsum[i]) - pos[i]); one 1024-thread block
__global__ __launch_bounds__(1024) void loss_kernel(
    const float* __restrict__ rowsum, const float* __restrict__ pos,
    float* __restrict__ out) {
  int t = threadIdx.x;
  const float4* r4 = (const float4*)rowsum;
  const float4* p4 = (const float4*)pos;
  float acc = 0.0f;
#pragma unroll
  for (int it = 0; it < 2; ++it) {
    int i = t + it * 1024;
    float4 r = r4[i], pv = p4[i];
    acc += 80.0f + __logf(r.x) + __logf(r.y) + __logf(r.z) + __logf(r.w)
           - pv.x - pv.y - pv.z - pv.w;
  }
#pragma unroll
  for (int m = 32; m; m >>= 1) acc += __shfl_xor(acc, m);
  __shared__ float wsum[16];
  if ((t & 63) == 0) wsum[t >> 6] = acc;
  __syncthreads();
  if (t == 0) {
    float tot = 0.0f;
#pragma unroll
    for (int i = 0; i < 16; ++i) tot += wsum[i];
    out[0] = tot / (float)N;
  }
}

extern "C" void kernel_launch(void* const* d_in, const int* in_sizes, int n_in,
                              void* d_out, int out_size, void* d_ws, size_t ws_size,
                              hipStream_t stream) {
  const float* x = (const float*)d_in[0];
  float* rowsum = (float*)d_ws;
  float* pos = rowsum + N;
  unsigned char* xn = (unsigned char*)(rowsum + 2 * N + 16);

  norm_kernel<<<N / 16, 256, 0, stream>>>(x, xn, rowsum);
  sim_kernel<<<592, 512, 0, stream>>>(xn, rowsum, pos);
  loss_kernel<<<1, 1024, 0, stream>>>(rowsum, pos, (float*)d_out);
}